// Round 2
// baseline (166.822 us; speedup 1.0000x reference)
//
#include <hip/hip_runtime.h>
#include <hip/hip_bf16.h>

#define N_NODES 50000
#define DEG 16
#define IN_DIM 256
#define OUT_DIM 64
#define HEADS 4
#define C_DIM 256   /* HEADS*OUT_DIM */
#define SLOPE 0.01f

static __device__ __forceinline__ float bf2f(unsigned int u16) {
    union { unsigned int i; float f; } v; v.i = (u16 & 0xffffu) << 16; return v.f;
}
static __device__ __forceinline__ unsigned short f2bf(float f) {
    union { float f; unsigned int i; } v; v.f = f;
    unsigned int u = v.i;
    return (unsigned short)((u + 0x7fffu + ((u >> 16) & 1u)) >> 16);  // RNE
}

// ---------------- Kernel 1: z[n][c] = sum_k h[n][k] * W[c/64][k][c%64], bf16 out
// Block tile: 64 nodes x 256 cols, BK=16, 256 threads, 8x8 register tile.
__global__ __launch_bounds__(256) void k_proj(const float* __restrict__ h,
                                              const float* __restrict__ W,
                                              unsigned short* __restrict__ z) {
    __shared__ float As[16 * 68];   // [kk][m], stride 68
    __shared__ float Bs[16 * 256];  // [kk][c]
    const int tid = threadIdx.x;
    const int mbase = blockIdx.x * 64;
    const int tm = tid >> 5;   // 0..7  -> nodes tm*8..tm*8+7
    const int tn = tid & 31;   // 0..31 -> cols  tn*8..tn*8+7

    float acc[8][8];
    #pragma unroll
    for (int i = 0; i < 8; i++)
        #pragma unroll
        for (int j = 0; j < 8; j++) acc[i][j] = 0.f;

    const int ar = tid >> 2;
    const int ak = (tid & 3) << 2;
    int arow = mbase + ar; if (arow >= N_NODES) arow = N_NODES - 1;
    const float* hrow = h + (size_t)arow * IN_DIM;
    const int bk = tid >> 4;
    const int bd = (tid & 15) << 2;

    for (int k0 = 0; k0 < IN_DIM; k0 += 16) {
        __syncthreads();
        float4 av = *(const float4*)(hrow + k0 + ak);
        As[(ak + 0) * 68 + ar] = av.x;
        As[(ak + 1) * 68 + ar] = av.y;
        As[(ak + 2) * 68 + ar] = av.z;
        As[(ak + 3) * 68 + ar] = av.w;
        #pragma unroll
        for (int hh = 0; hh < 4; hh++) {
            float4 bv = *(const float4*)(W + hh * (IN_DIM * OUT_DIM) + (k0 + bk) * OUT_DIM + bd);
            *(float4*)(&Bs[bk * 256 + hh * 64 + bd]) = bv;
        }
        __syncthreads();
        #pragma unroll
        for (int kk = 0; kk < 16; kk++) {
            float a[8], b[8];
            *(float4*)(a)     = *(const float4*)(&As[kk * 68 + tm * 8]);
            *(float4*)(a + 4) = *(const float4*)(&As[kk * 68 + tm * 8 + 4]);
            *(float4*)(b)     = *(const float4*)(&Bs[kk * 256 + tn * 8]);
            *(float4*)(b + 4) = *(const float4*)(&Bs[kk * 256 + tn * 8 + 4]);
            #pragma unroll
            for (int i = 0; i < 8; i++)
                #pragma unroll
                for (int j = 0; j < 8; j++)
                    acc[i][j] = fmaf(a[i], b[j], acc[i][j]);
        }
    }
    #pragma unroll
    for (int i = 0; i < 8; i++) {
        int m = mbase + tm * 8 + i;
        if (m < N_NODES) {
            unsigned short u[8];
            #pragma unroll
            for (int j = 0; j < 8; j++) u[j] = f2bf(acc[i][j]);
            *(uint4*)(z + (size_t)m * C_DIM + tn * 8) = *(const uint4*)u;
        }
    }
}

// ---------------- Kernel 1b: es[n][h] = z[n,h,:].a_src[h]; ed likewise. Wave per node.
__global__ __launch_bounds__(256) void k_escore(const unsigned short* __restrict__ z,
                                                const float* __restrict__ a_src,
                                                const float* __restrict__ a_dst,
                                                float* __restrict__ es,
                                                float* __restrict__ ed) {
    const int lane = threadIdx.x & 63;
    const int n = blockIdx.x * 4 + (threadIdx.x >> 6);
    const uint2 v = *(const uint2*)(z + (size_t)n * C_DIM + lane * 4);
    const float f0 = bf2f(v.x), f1 = bf2f(v.x >> 16), f2 = bf2f(v.y), f3 = bf2f(v.y >> 16);
    const float4 as4 = *(const float4*)(a_src + lane * 4);
    const float4 ad4 = *(const float4*)(a_dst + lane * 4);
    float ps = f0 * as4.x + f1 * as4.y + f2 * as4.z + f3 * as4.w;
    float pd = f0 * ad4.x + f1 * ad4.y + f2 * ad4.z + f3 * ad4.w;
    #pragma unroll
    for (int o = 1; o < 16; o <<= 1) {
        ps += __shfl_xor(ps, o, 64);
        pd += __shfl_xor(pd, o, 64);
    }
    if ((lane & 15) == 0) {
        const int hh = lane >> 4;
        es[n * 4 + hh] = ps;
        ed[n * 4 + hh] = pd;
    }
}

// ---------------- Kernel 2: per-node softmax over 16 incoming edges + weighted sum.
// Wave per node; lane (h=l>>4, j=l&15) does logits/softmax; then lane owns cols 4l..4l+3.
__global__ __launch_bounds__(256) void k_attn(const unsigned short* __restrict__ z,
                                              const float* __restrict__ es,
                                              const float* __restrict__ ed,
                                              const int* __restrict__ src,
                                              float* __restrict__ out) {
    const int lane = threadIdx.x & 63;
    const int n = blockIdx.x * 4 + (threadIdx.x >> 6);
    const int j16 = lane & 15;
    const int h4 = lane >> 4;

    const int s = src[n * DEG + j16];
    float e = es[s * 4 + h4] + ed[n * 4 + h4];
    e = (e >= 0.f) ? e : SLOPE * e;
    float m = e;
    #pragma unroll
    for (int o = 1; o < 16; o <<= 1) m = fmaxf(m, __shfl_xor(m, o, 64));
    const float ex = __expf(e - m);
    float sum = ex;
    #pragma unroll
    for (int o = 1; o < 16; o <<= 1) sum += __shfl_xor(sum, o, 64);
    const float alpha = ex / sum;

    float a0 = 0.f, a1 = 0.f, a2 = 0.f, a3 = 0.f;
    #pragma unroll
    for (int j = 0; j < 16; j++) {
        const int sj = __shfl(s, j, 64);
        const float al = __shfl(alpha, (h4 << 4) + j, 64);
        const uint2 v = *(const uint2*)(z + (size_t)sj * C_DIM + lane * 4);
        a0 = fmaf(al, bf2f(v.x), a0);
        a1 = fmaf(al, bf2f(v.x >> 16), a1);
        a2 = fmaf(al, bf2f(v.y), a2);
        a3 = fmaf(al, bf2f(v.y >> 16), a3);
    }
    float4 o4 = make_float4(a0, a1, a2, a3);
    *(float4*)(out + (size_t)n * C_DIM + lane * 4) = o4;
}

extern "C" void kernel_launch(void* const* d_in, const int* in_sizes, int n_in,
                              void* d_out, int out_size, void* d_ws, size_t ws_size,
                              hipStream_t stream) {
    const float* h     = (const float*)d_in[0];
    const float* W     = (const float*)d_in[1];
    const float* a_src = (const float*)d_in[2];
    const float* a_dst = (const float*)d_in[3];
    const int*   src   = (const int*)d_in[4];
    // d_in[5] (dst) is repeat(arange(N), DEG) -> implicit in indexing.

    unsigned short* z  = (unsigned short*)d_ws;                       // [N][256] bf16
    float* es = (float*)((char*)d_ws + (size_t)N_NODES * C_DIM * 2);  // [N][4]
    float* ed = es + (size_t)N_NODES * HEADS;                         // [N][4]
    float* out = (float*)d_out;

    hipLaunchKernelGGL(k_proj,   dim3((N_NODES + 63) / 64), dim3(256), 0, stream, h, W, z);
    hipLaunchKernelGGL(k_escore, dim3(N_NODES / 4),         dim3(256), 0, stream, z, a_src, a_dst, es, ed);
    hipLaunchKernelGGL(k_attn,   dim3(N_NODES / 4),         dim3(256), 0, stream, z, es, ed, src, out);
}

// Round 4
// 155.899 us; speedup vs baseline: 1.0701x; 1.0701x over previous
//
#include <hip/hip_runtime.h>
#include <hip/hip_bf16.h>

#define N_NODES 50000
#define DEG 16
#define IN_DIM 256
#define OUT_DIM 64
#define HEADS 4
#define C_DIM 256   /* HEADS*OUT_DIM */
#define SLOPE 0.01f

typedef __attribute__((ext_vector_type(8))) short short8;
typedef __attribute__((ext_vector_type(4))) float f32x4;

static __device__ __forceinline__ float bf2f(unsigned int u16) {
    union { unsigned int i; float f; } v; v.i = (u16 & 0xffffu) << 16; return v.f;
}
static __device__ __forceinline__ unsigned short f2bf(float f) {
    union { float f; unsigned int i; } v; v.f = f;
    unsigned int u = v.i;
    return (unsigned short)((u + 0x7fffu + ((u >> 16) & 1u)) >> 16);  // RNE
}
static __device__ __forceinline__ unsigned int cvt_pk_bf16(float lo, float hi) {
    unsigned int w;
    asm("v_cvt_pk_bf16_f32 %0, %1, %2" : "=v"(w) : "v"(lo), "v"(hi));
    return w;
}

// ---------------- Kernel 0: pack W[h][k][d] (f32) -> Bp[c][k] (bf16), c = h*64+d
__global__ __launch_bounds__(256) void k_prep(const float* __restrict__ W,
                                              unsigned short* __restrict__ Bp) {
    const int c = blockIdx.x;           // 0..255
    const int k = threadIdx.x;          // 0..255
    const int hh = c >> 6, d = c & 63;
    Bp[c * IN_DIM + k] = f2bf(W[hh * (IN_DIM * OUT_DIM) + k * OUT_DIM + d]);
}

// ---------------- Kernel 1: z[m][c] = sum_k h[m][k]*Wcat[k][c] via bf16 MFMA.
// Block: 256 thr = 4 waves. Each wave: 16 rows x 256 cols (16 col-tiles of 16x16x32 MFMA).
// Fused epilogue: es[m][h] = z[m]·a_src (per head), ed likewise.
__global__ __launch_bounds__(256) void k_proj(const float* __restrict__ h,
                                              const unsigned short* __restrict__ Bp,
                                              const float* __restrict__ a_src,
                                              const float* __restrict__ a_dst,
                                              unsigned short* __restrict__ z,
                                              float* __restrict__ es,
                                              float* __restrict__ ed) {
    const int lane = threadIdx.x & 63;
    const int wave = threadIdx.x >> 6;                 // 0..3
    const int wb   = blockIdx.x * 64 + wave * 16;      // wave's first row
    const int n    = lane & 15;                        // tile col / A row
    const int g    = lane >> 4;                        // k-group (0..3)

    int arow = wb + n; if (arow >= N_NODES) arow = N_NODES - 1;
    const float* hrow = h + (size_t)arow * IN_DIM;

    f32x4 acc[16];
    #pragma unroll
    for (int ct = 0; ct < 16; ct++) acc[ct] = (f32x4){0.f, 0.f, 0.f, 0.f};

    #pragma unroll
    for (int ks = 0; ks < 8; ks++) {
        const int k0 = ks * 32 + g * 8;
        // A fragment: 8 f32 -> 8 bf16 (element j of frag = k0+j, same mapping as B)
        float4 a0 = *(const float4*)(hrow + k0);
        float4 a1 = *(const float4*)(hrow + k0 + 4);
        union { unsigned int w[4]; short8 s; } au;
        au.w[0] = cvt_pk_bf16(a0.x, a0.y);
        au.w[1] = cvt_pk_bf16(a0.z, a0.w);
        au.w[2] = cvt_pk_bf16(a1.x, a1.y);
        au.w[3] = cvt_pk_bf16(a1.z, a1.w);
        const short8 af = au.s;
        #pragma unroll
        for (int ct = 0; ct < 16; ct++) {
            union { uint4 u; short8 s; } bu;
            bu.u = *(const uint4*)(Bp + (size_t)(ct * 16 + n) * IN_DIM + k0);
            acc[ct] = __builtin_amdgcn_mfma_f32_16x16x32_bf16(af, bu.s, acc[ct], 0, 0, 0);
        }
    }

    // ---- store z (D map: col = lane&15, row = (lane>>4)*4 + reg)
    const int g2 = lane >> 4;
    #pragma unroll
    for (int ct = 0; ct < 16; ct++) {
        #pragma unroll
        for (int r = 0; r < 4; r++) {
            const int m = wb + g2 * 4 + r;
            if (m < N_NODES) z[(size_t)m * C_DIM + ct * 16 + n] = f2bf(acc[ct][r]);
        }
    }

    // ---- fused es/ed: reduce over cols (16 lanes of this g2 group hold all 256 cols)
    float keep_s = 0.f, keep_d = 0.f;
    #pragma unroll
    for (int hh = 0; hh < 4; hh++) {
        #pragma unroll
        for (int r = 0; r < 4; r++) {
            float vs = 0.f, vd = 0.f;
            #pragma unroll
            for (int q = 0; q < 4; q++) {
                const int ct = hh * 4 + q;
                const int c  = ct * 16 + n;
                vs = fmaf(acc[ct][r], a_src[c], vs);
                vd = fmaf(acc[ct][r], a_dst[c], vd);
            }
            #pragma unroll
            for (int o = 1; o < 16; o <<= 1) {
                vs += __shfl_xor(vs, o, 64);
                vd += __shfl_xor(vd, o, 64);
            }
            if (n == (hh << 2 | r)) { keep_s = vs; keep_d = vd; }
        }
    }
    {
        const int m = wb + g2 * 4 + (n & 3);
        const int hh = n >> 2;
        if (m < N_NODES) {
            es[m * 4 + hh] = keep_s;
            ed[m * 4 + hh] = keep_d;
        }
    }
}

// ---------------- Kernel 2: per-node softmax over 16 incoming edges + weighted sum.
__global__ __launch_bounds__(256) void k_attn(const unsigned short* __restrict__ z,
                                              const float* __restrict__ es,
                                              const float* __restrict__ ed,
                                              const int* __restrict__ src,
                                              float* __restrict__ out) {
    const int lane = threadIdx.x & 63;
    const int n = blockIdx.x * 4 + (threadIdx.x >> 6);
    const int j16 = lane & 15;
    const int h4 = lane >> 4;

    const int s = src[n * DEG + j16];
    float e = es[s * 4 + h4] + ed[n * 4 + h4];
    e = (e >= 0.f) ? e : SLOPE * e;
    float m = e;
    #pragma unroll
    for (int o = 1; o < 16; o <<= 1) m = fmaxf(m, __shfl_xor(m, o, 64));
    const float ex = __expf(e - m);
    float sum = ex;
    #pragma unroll
    for (int o = 1; o < 16; o <<= 1) sum += __shfl_xor(sum, o, 64);
    const float alpha = ex / sum;

    float a0 = 0.f, a1 = 0.f, a2 = 0.f, a3 = 0.f;
    #pragma unroll
    for (int j = 0; j < 16; j++) {
        const int sj = __shfl(s, j, 64);
        const float al = __shfl(alpha, (h4 << 4) + j, 64);
        const uint2 v = *(const uint2*)(z + (size_t)sj * C_DIM + lane * 4);
        a0 = fmaf(al, bf2f(v.x), a0);
        a1 = fmaf(al, bf2f(v.x >> 16), a1);
        a2 = fmaf(al, bf2f(v.y), a2);
        a3 = fmaf(al, bf2f(v.y >> 16), a3);
    }
    float4 o4 = make_float4(a0, a1, a2, a3);
    *(float4*)(out + (size_t)n * C_DIM + lane * 4) = o4;
}

extern "C" void kernel_launch(void* const* d_in, const int* in_sizes, int n_in,
                              void* d_out, int out_size, void* d_ws, size_t ws_size,
                              hipStream_t stream) {
    const float* h     = (const float*)d_in[0];
    const float* W     = (const float*)d_in[1];
    const float* a_src = (const float*)d_in[2];
    const float* a_dst = (const float*)d_in[3];
    const int*   src   = (const int*)d_in[4];
    // d_in[5] (dst) is repeat(arange(N), DEG) -> implicit in indexing.

    unsigned short* z  = (unsigned short*)d_ws;                       // [N][256] bf16
    float* es = (float*)((char*)d_ws + (size_t)N_NODES * C_DIM * 2);  // [N][4] f32
    float* ed = es + (size_t)N_NODES * HEADS;                         // [N][4] f32
    unsigned short* Bp = (unsigned short*)((char*)d_ws +
                         (size_t)N_NODES * C_DIM * 2 +
                         (size_t)N_NODES * HEADS * 4 * 2);            // [256][256] bf16
    float* out = (float*)d_out;

    hipLaunchKernelGGL(k_prep, dim3(C_DIM),               dim3(IN_DIM), 0, stream, W, Bp);
    hipLaunchKernelGGL(k_proj, dim3((N_NODES + 63) / 64), dim3(256),    0, stream,
                       h, Bp, a_src, a_dst, z, es, ed);
    hipLaunchKernelGGL(k_attn, dim3(N_NODES / 4),         dim3(256),    0, stream,
                       z, es, ed, src, out);
}

// Round 5
// 99.654 us; speedup vs baseline: 1.6740x; 1.5644x over previous
//
#include <hip/hip_runtime.h>
#include <hip/hip_bf16.h>

#define N_NODES 50000
#define DEG 16
#define IN_DIM 256
#define OUT_DIM 64
#define HEADS 4
#define C_DIM 256   /* HEADS*OUT_DIM */
#define SLOPE 0.01f

typedef __attribute__((ext_vector_type(8))) short short8;
typedef __attribute__((ext_vector_type(4))) float f32x4;

static __device__ __forceinline__ float bf2f(unsigned int u16) {
    union { unsigned int i; float f; } v; v.i = (u16 & 0xffffu) << 16; return v.f;
}
static __device__ __forceinline__ unsigned short f2bf(float f) {
    union { float f; unsigned int i; } v; v.f = f;
    unsigned int u = v.i;
    return (unsigned short)((u + 0x7fffu + ((u >> 16) & 1u)) >> 16);  // RNE
}
static __device__ __forceinline__ unsigned int cvt_pk_bf16(float lo, float hi) {
    unsigned int w;
    asm("v_cvt_pk_bf16_f32 %0, %1, %2" : "=v"(w) : "v"(lo), "v"(hi));
    return w;
}
static __device__ __forceinline__ short8 pack8(float4 a0, float4 a1) {
    union { unsigned int w[4]; short8 s; } u;
    u.w[0] = cvt_pk_bf16(a0.x, a0.y);
    u.w[1] = cvt_pk_bf16(a0.z, a0.w);
    u.w[2] = cvt_pk_bf16(a1.x, a1.y);
    u.w[3] = cvt_pk_bf16(a1.z, a1.w);
    return u.s;
}

// ---------------- Kernel 0: pack W[h][k][d] (f32) -> Bp slice-major:
// Bp[(k>>6)*16384 + c*64 + (k&63)] (bf16), c = h*64+d.  (slice = 64 k's)
__global__ __launch_bounds__(256) void k_prep(const float* __restrict__ W,
                                              unsigned short* __restrict__ Bp) {
    const int c = blockIdx.x;           // 0..255
    const int k = threadIdx.x;          // 0..255
    const int hh = c >> 6, d = c & 63;
    Bp[(k >> 6) * 16384 + c * 64 + (k & 63)] =
        f2bf(W[hh * (IN_DIM * OUT_DIM) + k * OUT_DIM + d]);
}

// ---------------- Kernel 1: z = h @ Wcat via bf16 MFMA, LDS-staged B.
// Block: 256 thr = 4 waves, 64 rows/block (16 rows/wave), N=256 cols, K=256 in
// 4 slices of 64, double-buffered (2 x 32KB LDS).
// LDS slice layout: off(c,kk) = (kk>>5)*16384 + c*64 + ((kk>>3)&3)*16 + (kk&7)*2,
// swizzled off ^= ((c&7)<<4)  -> conflict-free b128 reads.
__global__ __launch_bounds__(256) void k_proj(const float* __restrict__ h,
                                              const unsigned short* __restrict__ Bp,
                                              const float* __restrict__ a_src,
                                              const float* __restrict__ a_dst,
                                              unsigned short* __restrict__ z,
                                              float* __restrict__ es,
                                              float* __restrict__ ed) {
    __shared__ unsigned char Bs[2][32768];
    const int tid  = threadIdx.x;
    const int lane = tid & 63;
    const int wave = tid >> 6;
    const int wb   = blockIdx.x * 64 + wave * 16;
    const int n    = lane & 15;        // tile col / A row
    const int g    = lane >> 4;        // k-group

    int arow = wb + n; if (arow >= N_NODES) arow = N_NODES - 1;
    const float* hrow = h + (size_t)arow * IN_DIM;

    // per-lane swizzled LDS read base: (n*64 + g*16) ^ ((n&7)<<4)   (bits <= 9)
    const int lbase = (n * 64 + g * 16) ^ ((n & 7) << 4);

    f32x4 acc[16];
    #pragma unroll
    for (int ct = 0; ct < 16; ct++) acc[ct] = (f32x4){0.f, 0.f, 0.f, 0.f};

    uint4  breg[8];
    float4 areg[4];
    short8 af0, af1;

    // ---- prologue: load slice 0 (B + A), stage B -> Bs[0], cvt A
    #pragma unroll
    for (int i = 0; i < 8; i++)
        breg[i] = *(const uint4*)((const char*)Bp + (size_t)(i * 256 + tid) * 16);
    #pragma unroll
    for (int ks2 = 0; ks2 < 2; ks2++) {
        areg[ks2 * 2]     = *(const float4*)(hrow + ks2 * 32 + g * 8);
        areg[ks2 * 2 + 1] = *(const float4*)(hrow + ks2 * 32 + g * 8 + 4);
    }
    #pragma unroll
    for (int i = 0; i < 8; i++) {
        const int L = i * 256 + tid;
        const int c = L >> 3, gg = L & 3, kk2 = (L >> 2) & 1;
        int woff = (kk2 << 14) + c * 64 + (gg << 4);
        woff ^= ((c & 7) << 4);
        *(uint4*)(&Bs[0][woff]) = breg[i];
    }
    af0 = pack8(areg[0], areg[1]);
    af1 = pack8(areg[2], areg[3]);
    __syncthreads();

    // ---- main loop over 4 K-slices, double buffered
    #pragma unroll
    for (int s = 0; s < 4; s++) {
        const int buf = s & 1;
        if (s < 3) {  // issue next slice's loads early (latency hides under MFMA)
            const char* bsrc = (const char*)Bp + (size_t)(s + 1) * 32768;
            #pragma unroll
            for (int i = 0; i < 8; i++)
                breg[i] = *(const uint4*)(bsrc + (size_t)(i * 256 + tid) * 16);
            #pragma unroll
            for (int ks2 = 0; ks2 < 2; ks2++) {
                areg[ks2 * 2]     = *(const float4*)(hrow + (s + 1) * 64 + ks2 * 32 + g * 8);
                areg[ks2 * 2 + 1] = *(const float4*)(hrow + (s + 1) * 64 + ks2 * 32 + g * 8 + 4);
            }
        }
        // compute current slice from LDS
        #pragma unroll
        for (int ct = 0; ct < 16; ct++) {
            union { uint4 u; short8 s8; } b0, b1;
            b0.u = *(const uint4*)(&Bs[buf][ct * 1024 + lbase]);
            b1.u = *(const uint4*)(&Bs[buf][16384 + ct * 1024 + lbase]);
            acc[ct] = __builtin_amdgcn_mfma_f32_16x16x32_bf16(af0, b0.s8, acc[ct], 0, 0, 0);
            acc[ct] = __builtin_amdgcn_mfma_f32_16x16x32_bf16(af1, b1.s8, acc[ct], 0, 0, 0);
        }
        if (s < 3) {
            #pragma unroll
            for (int i = 0; i < 8; i++) {
                const int L = i * 256 + tid;
                const int c = L >> 3, gg = L & 3, kk2 = (L >> 2) & 1;
                int woff = (kk2 << 14) + c * 64 + (gg << 4);
                woff ^= ((c & 7) << 4);
                *(uint4*)(&Bs[buf ^ 1][woff]) = breg[i];
            }
            af0 = pack8(areg[0], areg[1]);
            af1 = pack8(areg[2], areg[3]);
            __syncthreads();
        }
    }

    // ---- store z (D map: col = lane&15, row = (lane>>4)*4 + reg)
    const int g2 = lane >> 4;
    #pragma unroll
    for (int ct = 0; ct < 16; ct++) {
        #pragma unroll
        for (int r = 0; r < 4; r++) {
            const int m = wb + g2 * 4 + r;
            if (m < N_NODES) z[(size_t)m * C_DIM + ct * 16 + n] = f2bf(acc[ct][r]);
        }
    }

    // ---- fused es/ed
    float keep_s = 0.f, keep_d = 0.f;
    #pragma unroll
    for (int hh = 0; hh < 4; hh++) {
        #pragma unroll
        for (int r = 0; r < 4; r++) {
            float vs = 0.f, vd = 0.f;
            #pragma unroll
            for (int q = 0; q < 4; q++) {
                const int ct = hh * 4 + q;
                const int c  = ct * 16 + n;
                vs = fmaf(acc[ct][r], a_src[c], vs);
                vd = fmaf(acc[ct][r], a_dst[c], vd);
            }
            #pragma unroll
            for (int o = 1; o < 16; o <<= 1) {
                vs += __shfl_xor(vs, o, 64);
                vd += __shfl_xor(vd, o, 64);
            }
            if (n == (hh << 2 | r)) { keep_s = vs; keep_d = vd; }
        }
    }
    {
        const int m = wb + g2 * 4 + (n & 3);
        const int hh = n >> 2;
        if (m < N_NODES) {
            es[m * 4 + hh] = keep_s;
            ed[m * 4 + hh] = keep_d;
        }
    }
}

// ---------------- Kernel 2: per-node softmax over 16 incoming edges + weighted sum.
__global__ __launch_bounds__(256) void k_attn(const unsigned short* __restrict__ z,
                                              const float* __restrict__ es,
                                              const float* __restrict__ ed,
                                              const int* __restrict__ src,
                                              float* __restrict__ out) {
    const int lane = threadIdx.x & 63;
    const int n = blockIdx.x * 4 + (threadIdx.x >> 6);
    const int j16 = lane & 15;
    const int h4 = lane >> 4;

    const int s = src[n * DEG + j16];
    float e = es[s * 4 + h4] + ed[n * 4 + h4];
    e = (e >= 0.f) ? e : SLOPE * e;
    float m = e;
    #pragma unroll
    for (int o = 1; o < 16; o <<= 1) m = fmaxf(m, __shfl_xor(m, o, 64));
    const float ex = __expf(e - m);
    float sum = ex;
    #pragma unroll
    for (int o = 1; o < 16; o <<= 1) sum += __shfl_xor(sum, o, 64);
    const float alpha = ex / sum;

    float a0 = 0.f, a1 = 0.f, a2 = 0.f, a3 = 0.f;
    #pragma unroll
    for (int j = 0; j < 16; j++) {
        const int sj = __shfl(s, j, 64);
        const float al = __shfl(alpha, (h4 << 4) + j, 64);
        const uint2 v = *(const uint2*)(z + (size_t)sj * C_DIM + lane * 4);
        a0 = fmaf(al, bf2f(v.x), a0);
        a1 = fmaf(al, bf2f(v.x >> 16), a1);
        a2 = fmaf(al, bf2f(v.y), a2);
        a3 = fmaf(al, bf2f(v.y >> 16), a3);
    }
    float4 o4 = make_float4(a0, a1, a2, a3);
    *(float4*)(out + (size_t)n * C_DIM + lane * 4) = o4;
}

extern "C" void kernel_launch(void* const* d_in, const int* in_sizes, int n_in,
                              void* d_out, int out_size, void* d_ws, size_t ws_size,
                              hipStream_t stream) {
    const float* h     = (const float*)d_in[0];
    const float* W     = (const float*)d_in[1];
    const float* a_src = (const float*)d_in[2];
    const float* a_dst = (const float*)d_in[3];
    const int*   src   = (const int*)d_in[4];
    // d_in[5] (dst) is repeat(arange(N), DEG) -> implicit in indexing.

    unsigned short* z  = (unsigned short*)d_ws;                       // [N][256] bf16
    float* es = (float*)((char*)d_ws + (size_t)N_NODES * C_DIM * 2);  // [N][4] f32
    float* ed = es + (size_t)N_NODES * HEADS;                         // [N][4] f32
    unsigned short* Bp = (unsigned short*)((char*)d_ws +
                         (size_t)N_NODES * C_DIM * 2 +
                         (size_t)N_NODES * HEADS * 4 * 2);            // [4][256][64] bf16
    float* out = (float*)d_out;

    hipLaunchKernelGGL(k_prep, dim3(C_DIM),               dim3(IN_DIM), 0, stream, W, Bp);
    hipLaunchKernelGGL(k_proj, dim3((N_NODES + 63) / 64), dim3(256),    0, stream,
                       h, Bp, a_src, a_dst, z, es, ed);
    hipLaunchKernelGGL(k_attn, dim3(N_NODES / 4),         dim3(256),    0, stream,
                       z, es, ed, src, out);
}